// Round 8
// baseline (27.205 us; speedup 1.0000x reference)
//
#include <hip/hip_runtime.h>
#include <math.h>

// AttController: two cascaded PIDs (angle -> rate) + inertia coupling.
// 4 elements per thread. ALL AoS streams (J, ref, meas, omega) staged
// block-wide through LDS with float4 fully-contiguous coalesced loads;
// SoA state rows loaded as aligned float4 (4 consecutive elements);
// output stored as 3x NT float4. Every global access is 16B/lane.
// Dead-load elim: angle PID kd=0,tau=0 -> prev_err/d_filt rows 0-2 unused;
// rate axis 2 kd=0 -> row 5 unused. Essential traffic 124 MB.
// LDS 72 KB/block -> 2 blocks/CU; rounds 4-7 showed occupancy (31-61%) is
// not the limiter; this trades it for 2x memory-level parallelism/thread.
// Inputs (setup_inputs order), all float32:
//   0: ref_rpy (N,3)  1: meas_rpy (N,3)  2: meas_omegab (N,3)
//   3: J (N,3,3)      4: integ (6,N)     5: prev_err (6,N) rows 3,4 only
//   6: d_filt (6,N) rows 3,4 only
// Output: tau (N,3) float32.

typedef float v4f __attribute__((ext_vector_type(4)));

#define PI_F 3.14159265358979323846f
#define TWO_PI_F 6.28318530717958647692f
#define EPB 1024          // elements per block (256 threads x 4)
#define EPT 4             // elements per thread

__device__ __forceinline__ float wrap_yaw(float e) {
    if (e >  PI_F) e -= TWO_PI_F;
    if (e < -PI_F) e += TWO_PI_F;
    return e;
}

__device__ __forceinline__ void pid_and_tau(
    const float err0, const float err1, const float err2,
    const float w0, const float w1, const float w2,
    const float ig_a0, const float ig_a1, const float ig_a2,
    const float ig_r0, const float ig_r1, const float ig_r2,
    const float pe0, const float pe1,           // rate prev_err, axes 0,1
    const float df0, const float df1,           // rate d_filt,   axes 0,1
    const float* Jm,                            // 9 floats, row-major
    float& o0, float& o1, float& o2)
{
    // angle PID (tau=0 -> alpha=1; kd=0 -> no D term)
    const float DT_A = 0.01f;
    float u0 = 6.0f * err0 + 1.0f * (ig_a0 + err0 * DT_A);
    float u1 = 6.0f * err1 + 1.0f * (ig_a1 + err1 * DT_A);
    float u2 = 3.0f * err2 + 0.5f * (ig_a2 + err2 * DT_A);
    u0 = fminf(fmaxf(u0, -10.0f), 10.0f);
    u1 = fminf(fmaxf(u1, -10.0f), 10.0f);
    u2 = fminf(fmaxf(u2, -5.0f), 5.0f);

    // rate PID (axis 2: kd=0 -> D term exactly 0)
    const float DT_R = 0.002f;
    const float ALPHA_R = DT_R / (0.005f + DT_R);  // 2/7 in f32
    float e0 = u0 - w0, e1 = u1 - w1, e2 = u2 - w2;
    float dn0 = df0 + ALPHA_R * ((e0 - pe0) / DT_R - df0);
    float dn1 = df1 + ALPHA_R * ((e1 - pe1) / DT_R - df1);
    float a0 = 0.25f * e0 + 0.5f * (ig_r0 + e0 * DT_R) + 0.0025f * dn0;
    float a1 = 0.25f * e1 + 0.5f * (ig_r1 + e1 * DT_R) + 0.0025f * dn1;
    float a2 = 0.12f * e2 + 0.1f  * (ig_r2 + e2 * DT_R);
    a0 = fminf(fmaxf(a0, -1.0f), 1.0f);
    a1 = fminf(fmaxf(a1, -1.0f), 1.0f);
    a2 = fminf(fmaxf(a2, -0.5f), 0.5f);

    // tau = J*alpha + w x (J*w)
    float Jw0 = Jm[0]*w0 + Jm[1]*w1 + Jm[2]*w2;
    float Jw1 = Jm[3]*w0 + Jm[4]*w1 + Jm[5]*w2;
    float Jw2 = Jm[6]*w0 + Jm[7]*w1 + Jm[8]*w2;
    float Ja0 = Jm[0]*a0 + Jm[1]*a1 + Jm[2]*a2;
    float Ja1 = Jm[3]*a0 + Jm[4]*a1 + Jm[5]*a2;
    float Ja2 = Jm[6]*a0 + Jm[7]*a1 + Jm[8]*a2;
    o0 = Ja0 + (w1 * Jw2 - w2 * Jw1);
    o1 = Ja1 + (w2 * Jw0 - w0 * Jw2);
    o2 = Ja2 + (w0 * Jw1 - w1 * Jw0);
}

__global__ __launch_bounds__(256) void att_ctrl_v8(
    const float* __restrict__ ref_rpy,
    const float* __restrict__ meas_rpy,
    const float* __restrict__ meas_omegab,
    const float* __restrict__ J,
    const float* __restrict__ integ,
    const float* __restrict__ prev_err,
    const float* __restrict__ d_filt,
    float* __restrict__ out,
    int n)
{
    __shared__ float Jl[EPB * 9];   // 36 KB
    __shared__ float Rl[EPB * 3];   // 12 KB
    __shared__ float Ml[EPB * 3];   // 12 KB
    __shared__ float Wl[EPB * 3];   // 12 KB  -> 72 KB total, 2 blocks/CU

    const int tid = threadIdx.x;
    const long long blkBase = (long long)EPB * blockIdx.x;
    const long long rem = (long long)n - blkBase;
    const int elemsInBlk = (int)(rem < EPB ? rem : EPB);
    const long long e0 = blkBase + (long long)EPT * tid;     // first element
    const bool full = (e0 + EPT <= (long long)n);

    const float* Jg = J           + 9 * blkBase;   // 36864B/blk -> 16B aligned
    const float* Rg = ref_rpy     + 3 * blkBase;   // 12288B/blk -> 16B aligned
    const float* Mg = meas_rpy    + 3 * blkBase;
    const float* Wg = meas_omegab + 3 * blkBase;

    if (elemsInBlk == EPB) {
        // ---- full tile: float4 staging, fully contiguous 16B/lane ----
        #pragma unroll
        for (int it = 0; it < 9; ++it) {          // EPB*9/4 / 256 = 9
            int q = it * 256 + tid;
            *(v4f*)&Jl[4 * q] = *(const v4f*)(Jg + 4 * q);
        }
        #pragma unroll
        for (int it = 0; it < 3; ++it) {          // EPB*3/4 / 256 = 3
            int q = it * 256 + tid;
            *(v4f*)&Rl[4 * q] = *(const v4f*)(Rg + 4 * q);
            *(v4f*)&Ml[4 * q] = *(const v4f*)(Mg + 4 * q);
            *(v4f*)&Wl[4 * q] = *(const v4f*)(Wg + 4 * q);
        }
    } else {
        // ---- tail tile (last block only): scalar staging ----
        for (int f = tid; f < elemsInBlk * 9; f += 256) Jl[f] = Jg[f];
        for (int f = tid; f < elemsInBlk * 3; f += 256) {
            Rl[f] = Rg[f]; Ml[f] = Mg[f]; Wl[f] = Wg[f];
        }
    }

    // ---- SoA state loads: aligned float4 (4 consecutive elements) ----
    float iga[12], igr[12], pe[8], df[8];
    if (full) {
        #pragma unroll
        for (int k = 0; k < 3; ++k) {
            *(v4f*)&iga[4*k] = *(const v4f*)(integ + (size_t)k       * n + e0);
            *(v4f*)&igr[4*k] = *(const v4f*)(integ + (size_t)(k + 3) * n + e0);
        }
        #pragma unroll
        for (int k = 0; k < 2; ++k) {   // only rate axes 0,1 need pe/df
            *(v4f*)&pe[4*k] = *(const v4f*)(prev_err + (size_t)(k + 3) * n + e0);
            *(v4f*)&df[4*k] = *(const v4f*)(d_filt   + (size_t)(k + 3) * n + e0);
        }
    }

    __syncthreads();   // tiles resident in LDS

    if (full) {
        // per-thread LDS reads: contiguous per-thread slabs, v4f
        float r[12], m[12], w[12], Jm[36], o[12];
        #pragma unroll
        for (int q = 0; q < 3; ++q) {
            *(v4f*)&r[4*q] = *(const v4f*)&Rl[12 * tid + 4 * q];
            *(v4f*)&m[4*q] = *(const v4f*)&Ml[12 * tid + 4 * q];
            *(v4f*)&w[4*q] = *(const v4f*)&Wl[12 * tid + 4 * q];
        }
        #pragma unroll
        for (int q = 0; q < 9; ++q)
            *(v4f*)&Jm[4*q] = *(const v4f*)&Jl[36 * tid + 4 * q];

        #pragma unroll
        for (int j = 0; j < EPT; ++j) {
            float e0_ = r[3*j+0] - m[3*j+0];
            float e1_ = r[3*j+1] - m[3*j+1];
            float e2_ = wrap_yaw(r[3*j+2] - m[3*j+2]);
            pid_and_tau(e0_, e1_, e2_,
                        w[3*j+0], w[3*j+1], w[3*j+2],
                        iga[0*4+j], iga[1*4+j], iga[2*4+j],
                        igr[0*4+j], igr[1*4+j], igr[2*4+j],
                        pe[0*4+j], pe[1*4+j],
                        df[0*4+j], df[1*4+j],
                        &Jm[9*j],
                        o[3*j+0], o[3*j+1], o[3*j+2]);
        }

        #pragma unroll
        for (int q = 0; q < 3; ++q) {
            v4f v = *(const v4f*)&o[4*q];
            __builtin_nontemporal_store(v, (v4f*)(out + 12LL * ( (long long)blockIdx.x * 256 + tid) + 4 * q));
        }
    } else {
        // ---- partial thread at the global tail: scalar per element ----
        for (int j = 0; j < EPT; ++j) {
            const long long i = e0 + j;
            if (i >= (long long)n) break;
            const int li = (int)(i - blkBase);
            float ee0 = Rl[3*li+0] - Ml[3*li+0];
            float ee1 = Rl[3*li+1] - Ml[3*li+1];
            float ee2 = wrap_yaw(Rl[3*li+2] - Ml[3*li+2]);
            float w0 = Wl[3*li+0], w1 = Wl[3*li+1], w2 = Wl[3*li+2];
            float Jms[9];
            #pragma unroll
            for (int q = 0; q < 9; ++q) Jms[q] = Jl[9*li + q];
            float o0, o1, o2;
            pid_and_tau(ee0, ee1, ee2, w0, w1, w2,
                        integ[0*(size_t)n+i], integ[1*(size_t)n+i], integ[2*(size_t)n+i],
                        integ[3*(size_t)n+i], integ[4*(size_t)n+i], integ[5*(size_t)n+i],
                        prev_err[3*(size_t)n+i], prev_err[4*(size_t)n+i],
                        d_filt[3*(size_t)n+i], d_filt[4*(size_t)n+i],
                        Jms, o0, o1, o2);
            out[3*i+0] = o0; out[3*i+1] = o1; out[3*i+2] = o2;
        }
    }
}

extern "C" void kernel_launch(void* const* d_in, const int* in_sizes, int n_in,
                              void* d_out, int out_size, void* d_ws, size_t ws_size,
                              hipStream_t stream) {
    const float* ref_rpy     = (const float*)d_in[0];
    const float* meas_rpy    = (const float*)d_in[1];
    const float* meas_omegab = (const float*)d_in[2];
    const float* J           = (const float*)d_in[3];
    const float* integ       = (const float*)d_in[4];
    const float* prev_err    = (const float*)d_in[5];
    const float* d_filt      = (const float*)d_in[6];
    float* out = (float*)d_out;

    int n = in_sizes[0] / 3;                 // ref_rpy is (N,3)
    int grid = (n + EPB - 1) / EPB;          // one block per 1024 elements
    att_ctrl_v8<<<grid, 256, 0, stream>>>(
        ref_rpy, meas_rpy, meas_omegab, J, integ, prev_err, d_filt, out, n);
}

// Round 9
// 23.850 us; speedup vs baseline: 1.1407x; 1.1407x over previous
//
#include <hip/hip_runtime.h>
#include <math.h>

// AttController: two cascaded PIDs (angle -> rate) + inertia coupling.
// FINAL (best of 8 rounds, 24.13 us): 2 elements per thread; J (58% of input
// bytes) staged block-wide through LDS with float4 (16B/lane) coalesced
// loads; other streams dwordx2; NT dwordx2 stores.
// Dead-load elim: angle PID kd=0,tau=0 -> prev_err/d_filt rows 0-2 unused;
// rate axis 2 kd=0 -> row 5 unused. Essential traffic 124 MB -> ~5.1 TB/s
// effective (mixed L3/HBM service ceiling for this 7-stream pattern; the
// harness's 268MB inter-replay fill evicts L3, forcing ~55MB/dispatch HBM).
// Levers falsified: bytes, occupancy 16-61%, block size, width on non-J
// streams, 4 elem/thread (2x regression risk at <20% occupancy).
// Inputs (setup_inputs order), all float32:
//   0: ref_rpy (N,3)  1: meas_rpy (N,3)  2: meas_omegab (N,3)
//   3: J (N,3,3)      4: integ (6,N)     5: prev_err (6,N) rows 3,4 only
//   6: d_filt (6,N) rows 3,4 only
// Output: tau (N,3) float32.

typedef float v2f __attribute__((ext_vector_type(2)));
typedef float v4f __attribute__((ext_vector_type(4)));

#define PI_F 3.14159265358979323846f
#define TWO_PI_F 6.28318530717958647692f
#define EPB 512   // elements per block (256 threads x 2)

__device__ __forceinline__ float wrap_yaw(float e) {
    if (e >  PI_F) e -= TWO_PI_F;
    if (e < -PI_F) e += TWO_PI_F;
    return e;
}

__device__ __forceinline__ void pid_and_tau(
    const float err0, const float err1, const float err2,
    const float w0, const float w1, const float w2,
    const float ig_a0, const float ig_a1, const float ig_a2,
    const float ig_r0, const float ig_r1, const float ig_r2,
    const float pe0, const float pe1,           // rate prev_err, axes 0,1
    const float df0, const float df1,           // rate d_filt,   axes 0,1
    const float* Jm,                            // 9 floats, row-major
    float& o0, float& o1, float& o2)
{
    // angle PID (tau=0 -> alpha=1; kd=0 -> no D term)
    const float DT_A = 0.01f;
    float u0 = 6.0f * err0 + 1.0f * (ig_a0 + err0 * DT_A);
    float u1 = 6.0f * err1 + 1.0f * (ig_a1 + err1 * DT_A);
    float u2 = 3.0f * err2 + 0.5f * (ig_a2 + err2 * DT_A);
    u0 = fminf(fmaxf(u0, -10.0f), 10.0f);
    u1 = fminf(fmaxf(u1, -10.0f), 10.0f);
    u2 = fminf(fmaxf(u2, -5.0f), 5.0f);

    // rate PID (axis 2: kd=0 -> D term exactly 0)
    const float DT_R = 0.002f;
    const float ALPHA_R = DT_R / (0.005f + DT_R);  // 2/7 in f32
    float e0 = u0 - w0, e1 = u1 - w1, e2 = u2 - w2;
    float dn0 = df0 + ALPHA_R * ((e0 - pe0) / DT_R - df0);
    float dn1 = df1 + ALPHA_R * ((e1 - pe1) / DT_R - df1);
    float a0 = 0.25f * e0 + 0.5f * (ig_r0 + e0 * DT_R) + 0.0025f * dn0;
    float a1 = 0.25f * e1 + 0.5f * (ig_r1 + e1 * DT_R) + 0.0025f * dn1;
    float a2 = 0.12f * e2 + 0.1f  * (ig_r2 + e2 * DT_R);
    a0 = fminf(fmaxf(a0, -1.0f), 1.0f);
    a1 = fminf(fmaxf(a1, -1.0f), 1.0f);
    a2 = fminf(fmaxf(a2, -0.5f), 0.5f);

    // tau = J*alpha + w x (J*w)
    float Jw0 = Jm[0]*w0 + Jm[1]*w1 + Jm[2]*w2;
    float Jw1 = Jm[3]*w0 + Jm[4]*w1 + Jm[5]*w2;
    float Jw2 = Jm[6]*w0 + Jm[7]*w1 + Jm[8]*w2;
    float Ja0 = Jm[0]*a0 + Jm[1]*a1 + Jm[2]*a2;
    float Ja1 = Jm[3]*a0 + Jm[4]*a1 + Jm[5]*a2;
    float Ja2 = Jm[6]*a0 + Jm[7]*a1 + Jm[8]*a2;
    o0 = Ja0 + (w1 * Jw2 - w2 * Jw1);
    o1 = Ja1 + (w2 * Jw0 - w0 * Jw2);
    o2 = Ja2 + (w0 * Jw1 - w1 * Jw0);
}

__global__ __launch_bounds__(256) void att_ctrl_v6(
    const float* __restrict__ ref_rpy,
    const float* __restrict__ meas_rpy,
    const float* __restrict__ meas_omegab,
    const float* __restrict__ J,
    const float* __restrict__ integ,
    const float* __restrict__ prev_err,
    const float* __restrict__ d_filt,
    float* __restrict__ out,
    int n)
{
    __shared__ float Jl[EPB * 9];   // 18 KB: J tile for this block's 512 elems

    const int tid = threadIdx.x;
    const long long blkBase = (long long)EPB * blockIdx.x;   // element base
    const int elemsInBlk = (int)((n - blkBase < EPB) ? (n - blkBase) : EPB);
    const long long t = (long long)blockIdx.x * 256 + tid;   // pair index
    const long long base = 2LL * t;                          // element index

    // ---- stage J tile: contiguous float4 loads (16B/lane, fully coalesced) ----
    const float* Jg = J + 9 * blkBase;       // 18432B*blockIdx -> 16B aligned
    const int jFloats = elemsInBlk * 9;
    const int jF4 = jFloats >> 2;
    for (int q = tid; q < jF4; q += 256)
        *(v4f*)&Jl[4 * q] = *(const v4f*)(Jg + 4 * q);
    for (int f = (jF4 << 2) + tid; f < jFloats; f += 256)   // 0-3 leftover floats
        Jl[f] = Jg[f];

    // ---- issue remaining global loads into registers before the barrier ----
    const bool full = (base + 2 <= (long long)n);
    float r[6], m[6], w[6], o[6];
    float iga[6], igr[6], pe[4], df[4];
    if (full) {
        #pragma unroll
        for (int q = 0; q < 3; ++q) {
            *(v2f*)&r[2*q] = *(const v2f*)(ref_rpy     + 6*t + 2*q);
            *(v2f*)&m[2*q] = *(const v2f*)(meas_rpy    + 6*t + 2*q);
            *(v2f*)&w[2*q] = *(const v2f*)(meas_omegab + 6*t + 2*q);
        }
        #pragma unroll
        for (int k = 0; k < 3; ++k) {
            *(v2f*)&iga[2*k] = *(const v2f*)(integ + (size_t)k       * n + base);
            *(v2f*)&igr[2*k] = *(const v2f*)(integ + (size_t)(k + 3) * n + base);
        }
        #pragma unroll
        for (int k = 0; k < 2; ++k) {   // only rate axes 0,1 need pe/df
            *(v2f*)&pe[2*k] = *(const v2f*)(prev_err + (size_t)(k + 3) * n + base);
            *(v2f*)&df[2*k] = *(const v2f*)(d_filt   + (size_t)(k + 3) * n + base);
        }
    }

    __syncthreads();   // J tile resident in LDS

    if (full) {
        // read both elements' J from LDS (ds_read_b64 x9, 8B aligned)
        float Jm[18];
        #pragma unroll
        for (int k = 0; k < 9; ++k)
            *(v2f*)&Jm[2*k] = *(const v2f*)&Jl[18 * tid + 2 * k];

        #pragma unroll
        for (int j = 0; j < 2; ++j) {
            float e0 = r[3*j+0] - m[3*j+0];
            float e1 = r[3*j+1] - m[3*j+1];
            float e2 = wrap_yaw(r[3*j+2] - m[3*j+2]);
            pid_and_tau(e0, e1, e2,
                        w[3*j+0], w[3*j+1], w[3*j+2],
                        iga[0*2+j], iga[1*2+j], iga[2*2+j],
                        igr[0*2+j], igr[1*2+j], igr[2*2+j],
                        pe[0*2+j], pe[1*2+j],
                        df[0*2+j], df[1*2+j],
                        &Jm[9*j],
                        o[3*j+0], o[3*j+1], o[3*j+2]);
        }

        #pragma unroll
        for (int q = 0; q < 3; ++q) {
            v2f v = *(const v2f*)&o[2*q];
            __builtin_nontemporal_store(v, (v2f*)(out + 6*t + 2*q));
        }
    } else if (base < (long long)n) {
        // ---- scalar tail (n odd): J already staged for this element too ----
        const long long i = base;
        float e0 = ref_rpy[3*i+0] - meas_rpy[3*i+0];
        float e1 = ref_rpy[3*i+1] - meas_rpy[3*i+1];
        float e2 = wrap_yaw(ref_rpy[3*i+2] - meas_rpy[3*i+2]);
        float w0 = meas_omegab[3*i+0], w1 = meas_omegab[3*i+1], w2 = meas_omegab[3*i+2];
        float Jm[9];
        #pragma unroll
        for (int q = 0; q < 9; ++q) Jm[q] = Jl[18 * tid + q];
        float o0, o1, o2;
        pid_and_tau(e0, e1, e2, w0, w1, w2,
                    integ[0*(size_t)n+i], integ[1*(size_t)n+i], integ[2*(size_t)n+i],
                    integ[3*(size_t)n+i], integ[4*(size_t)n+i], integ[5*(size_t)n+i],
                    prev_err[3*(size_t)n+i], prev_err[4*(size_t)n+i],
                    d_filt[3*(size_t)n+i], d_filt[4*(size_t)n+i],
                    Jm, o0, o1, o2);
        out[3*i+0] = o0; out[3*i+1] = o1; out[3*i+2] = o2;
    }
}

extern "C" void kernel_launch(void* const* d_in, const int* in_sizes, int n_in,
                              void* d_out, int out_size, void* d_ws, size_t ws_size,
                              hipStream_t stream) {
    const float* ref_rpy     = (const float*)d_in[0];
    const float* meas_rpy    = (const float*)d_in[1];
    const float* meas_omegab = (const float*)d_in[2];
    const float* J           = (const float*)d_in[3];
    const float* integ       = (const float*)d_in[4];
    const float* prev_err    = (const float*)d_in[5];
    const float* d_filt      = (const float*)d_in[6];
    float* out = (float*)d_out;

    int n = in_sizes[0] / 3;                 // ref_rpy is (N,3)
    int grid = (n + EPB - 1) / EPB;          // one block per 512 elements
    att_ctrl_v6<<<grid, 256, 0, stream>>>(
        ref_rpy, meas_rpy, meas_omegab, J, integ, prev_err, d_filt, out, n);
}